// Round 3
// baseline (196.606 us; speedup 1.0000x reference)
//
#include <hip/hip_runtime.h>
#include <hip/hip_bf16.h>
#include <math.h>

#define Nn 4096
#define Hdim 256
#define Edim 128
#define Cdim 32
#define Vdim 64
#define Kdim 20
#define G4H 1024
#define OUTS 513

// bucketing workspace (ints)
#define SK 512
#define SC 256
#define RK_OFF 64
#define RC_OFF (RK_OFF + Kdim * SK)

#define LSTM_BLOCKS (Kdim * 8 * 4)   // 640 = k(20) x s(8) x hq(4)
#define LOSS_BLOCKS (Cdim * 8)       // 256 = c(32) x s(8)
#define MAIN_GRID (LSTM_BLOCKS + LOSS_BLOCKS)  // 896

typedef short bf16x8 __attribute__((ext_vector_type(8)));
typedef float f32x4 __attribute__((ext_vector_type(4)));

__device__ __forceinline__ float sigmoidf_(float x) { return 1.0f / (1.0f + expf(-x)); }

__device__ __forceinline__ bf16x8 cvt8(float4 f0, float4 f1) {
    bf16x8 r;
    __hip_bfloat16 h;
    h = __float2bfloat16(f0.x); r[0] = *(short*)&h;
    h = __float2bfloat16(f0.y); r[1] = *(short*)&h;
    h = __float2bfloat16(f0.z); r[2] = *(short*)&h;
    h = __float2bfloat16(f0.w); r[3] = *(short*)&h;
    h = __float2bfloat16(f1.x); r[4] = *(short*)&h;
    h = __float2bfloat16(f1.y); r[5] = *(short*)&h;
    h = __float2bfloat16(f1.z); r[6] = *(short*)&h;
    h = __float2bfloat16(f1.w); r[7] = *(short*)&h;
    return r;
}

// ================= setup: bucket rows by cell_id / category =================
__global__ __launch_bounds__(1024) void k_bucket(const int* __restrict__ cell_id,
                                                 const int* __restrict__ category,
                                                 int* __restrict__ ws) {
    __shared__ int cnt[32];
    int t = threadIdx.x;
    if (t < 32) cnt[t] = 0;
    __syncthreads();
    int i0 = t * 4;
    if (blockIdx.x == 0) {
        int4 v = ((const int4*)cell_id)[t];
        int r;
        r = atomicAdd(&cnt[v.x], 1); if (r < SK) ws[RK_OFF + v.x * SK + r] = i0 + 0;
        r = atomicAdd(&cnt[v.y], 1); if (r < SK) ws[RK_OFF + v.y * SK + r] = i0 + 1;
        r = atomicAdd(&cnt[v.z], 1); if (r < SK) ws[RK_OFF + v.z * SK + r] = i0 + 2;
        r = atomicAdd(&cnt[v.w], 1); if (r < SK) ws[RK_OFF + v.w * SK + r] = i0 + 3;
        __syncthreads();
        if (t < 32) ws[t] = min(cnt[t], SK);
    } else {
        int4 v = ((const int4*)category)[t];
        int r;
        r = atomicAdd(&cnt[v.x], 1); if (r < SC) ws[RC_OFF + v.x * SC + r] = i0 + 0;
        r = atomicAdd(&cnt[v.y], 1); if (r < SC) ws[RC_OFF + v.y * SC + r] = i0 + 1;
        r = atomicAdd(&cnt[v.z], 1); if (r < SC) ws[RC_OFF + v.z * SC + r] = i0 + 2;
        r = atomicAdd(&cnt[v.w], 1); if (r < SC) ws[RC_OFF + v.w * SC + r] = i0 + 3;
        __syncthreads();
        if (t < 32) ws[32 + t] = min(cnt[t], SC);
    }
}

// ================= main: direct fp32 per-lane fragment loads + in-reg cvt + MFMA =================
// Fragment convention (mfma_f32_16x16x32_bf16), as verified in prior rounds:
// lane l = 16*q + r holds M[row r][k = 8q .. 8q+7] as 8 bf16.
__global__ __launch_bounds__(256, 2) void k_main(
    const float* __restrict__ vec, const float* __restrict__ inp,
    const float* __restrict__ h_prev, const float* __restrict__ c_prev,
    const float* __restrict__ Wlin, const float* __restrict__ blin,
    const float* __restrict__ Wec, const float* __restrict__ bec,
    const float* __restrict__ Wrel, const float* __restrict__ brel,
    const float* __restrict__ W_ih, const float* __restrict__ b_ih,
    const float* __restrict__ W_hh, const float* __restrict__ b_hh,
    const int* __restrict__ true_idx, const int* __restrict__ ec_idx, const int* __restrict__ rel_idx,
    const int* __restrict__ ws,
    float* __restrict__ out)
{
    int b = blockIdx.x, t = threadIdx.x;
    int wv = t >> 6, l = t & 63;
    int l15 = l & 15, quad = l >> 4;
    __shared__ float Lg[32 * 84];

    if (b < LSTM_BLOCKS) {
        // ---- LSTM: (k, s, hq); 64 rows x 64 h-cols x 4 gates; K = 384 ----
        int k = b >> 5; int s = (b >> 2) & 7; int hq = b & 3;
        int cntk = ws[k];
        int rcount = min(64, cntk - s * 64);
        if (rcount <= 0) return;

        int reg_row = ws[RK_OFF + k * SK + s * 64 + min(l, rcount - 1)];

        // per-lane A-operand bases: row r = l15 of tile m
        const float* xbi[4]; const float* xbh[4];
        #pragma unroll
        for (int m = 0; m < 4; m++) {
            int xr = __shfl(reg_row, m * 16 + l15);
            xbi[m] = inp    + (size_t)xr * Edim + quad * 8;
            xbh[m] = h_prev + (size_t)xr * Hdim + quad * 8;
        }
        // per-lane B-operand bases: W row = g*Hdim + hq*64 + wv*16 + l15
        int wrow = hq * 64 + wv * 16 + l15;
        const float* wbi[4]; const float* wbh[4];
        #pragma unroll
        for (int g = 0; g < 4; g++) {
            wbi[g] = W_ih + ((size_t)k * G4H + g * Hdim + wrow) * Edim + quad * 8;
            wbh[g] = W_hh + ((size_t)k * G4H + g * Hdim + wrow) * Hdim + quad * 8;
        }

        // hoist bias loads (independent of GEMM)
        int h = hq * 64 + wv * 16 + l15;
        float bs[4];
        #pragma unroll
        for (int g = 0; g < 4; g++)
            bs[g] = b_ih[(size_t)k * G4H + g * Hdim + h] + b_hh[(size_t)k * G4H + g * Hdim + h];

        f32x4 acc[4][4];
        #pragma unroll
        for (int m = 0; m < 4; m++)
            #pragma unroll
            for (int g = 0; g < 4; g++)
                acc[m][g] = (f32x4){0.f, 0.f, 0.f, 0.f};

        // prologue: stage-0 fp32 fragments
        float4 fx[4][2], fw[4][2];
        #pragma unroll
        for (int m = 0; m < 4; m++) {
            fx[m][0] = *(const float4*)(xbi[m]);
            fx[m][1] = *(const float4*)(xbi[m] + 4);
        }
        #pragma unroll
        for (int g = 0; g < 4; g++) {
            fw[g][0] = *(const float4*)(wbi[g]);
            fw[g][1] = *(const float4*)(wbi[g] + 4);
        }

        #pragma unroll
        for (int st = 0; st < 12; st++) {
            // consume current fp32 into bf16 frags (frees fx/fw)
            bf16x8 af[4], bfr[4];
            #pragma unroll
            for (int m = 0; m < 4; m++) af[m] = cvt8(fx[m][0], fx[m][1]);
            #pragma unroll
            for (int g = 0; g < 4; g++) bfr[g] = cvt8(fw[g][0], fw[g][1]);
            // issue next stage's loads before the MFMAs
            if (st < 11) {
                int s1 = st + 1;
                #pragma unroll
                for (int g = 0; g < 4; g++) {
                    const float* p = (s1 < 4) ? wbi[g] + s1 * 32 : wbh[g] + (s1 - 4) * 32;
                    fw[g][0] = *(const float4*)p;
                    fw[g][1] = *(const float4*)(p + 4);
                }
                #pragma unroll
                for (int m = 0; m < 4; m++) {
                    const float* p = (s1 < 4) ? xbi[m] + s1 * 32 : xbh[m] + (s1 - 4) * 32;
                    fx[m][0] = *(const float4*)p;
                    fx[m][1] = *(const float4*)(p + 4);
                }
            }
            #pragma unroll
            for (int m = 0; m < 4; m++)
                #pragma unroll
                for (int g = 0; g < 4; g++)
                    acc[m][g] = __builtin_amdgcn_mfma_f32_16x16x32_bf16(af[m], bfr[g], acc[m][g], 0, 0, 0);
        }

        #pragma unroll
        for (int m = 0; m < 4; m++) {
            #pragma unroll
            for (int reg = 0; reg < 4; reg++) {
                int r = m * 16 + quad * 4 + reg;
                int row = __shfl(reg_row, r);
                if (r < rcount) {
                    float iv = acc[m][0][reg] + bs[0];
                    float fv = acc[m][1][reg] + bs[1];
                    float gv = acc[m][2][reg] + bs[2];
                    float ov = acc[m][3][reg] + bs[3];
                    float cp = c_prev[(size_t)row * Hdim + h];
                    float cn = sigmoidf_(fv) * cp + sigmoidf_(iv) * tanhf(gv);
                    float hn = sigmoidf_(ov) * tanhf(cn);
                    out[(size_t)row * OUTS + 1 + h] = hn;
                    out[(size_t)row * OUTS + 1 + Hdim + h] = cn;
                }
            }
        }
    } else {
        // ---- loss: (c, s); 32 rows x 80 logits; K = 256 ----
        int b2 = b - LSTM_BLOCKS; int c = b2 >> 3; int s = b2 & 7;
        int cntc = ws[32 + c];
        int rcount = min(32, cntc - s * 32);
        if (rcount <= 0) return;

        int reg_row = ws[RC_OFF + c * SC + s * 32 + min(l & 31, rcount - 1)];

        const float* vb[2];
        #pragma unroll
        for (int m = 0; m < 2; m++) {
            int xr = __shfl(reg_row, m * 16 + l15);
            vb[m] = vec + (size_t)xr * Hdim + quad * 8;
        }
        const float* wb0 = Wlin + ((size_t)c * Vdim + wv * 16 + l15) * Hdim + quad * 8;
        // wave 3 also covers logit rows 64..79 (2 Wec + 5 Wrel + pad)
        const float* wb1 = nullptr;
        if (wv == 3) {
            if (l15 < 2)      wb1 = Wec + (size_t)l15 * Hdim + quad * 8;
            else if (l15 < 7) wb1 = Wrel + (size_t)(l15 - 2) * Hdim + quad * 8;
        }

        f32x4 a0[2], a1[2];
        #pragma unroll
        for (int m = 0; m < 2; m++) { a0[m] = (f32x4){0.f,0.f,0.f,0.f}; a1[m] = (f32x4){0.f,0.f,0.f,0.f}; }

        float4 fv0[2][2], fw0[2], fw1[2];
        #pragma unroll
        for (int m = 0; m < 2; m++) {
            fv0[m][0] = *(const float4*)(vb[m]);
            fv0[m][1] = *(const float4*)(vb[m] + 4);
        }
        fw0[0] = *(const float4*)(wb0);
        fw0[1] = *(const float4*)(wb0 + 4);
        if (wb1) { fw1[0] = *(const float4*)(wb1); fw1[1] = *(const float4*)(wb1 + 4); }
        else     { fw1[0] = (float4){0,0,0,0};     fw1[1] = (float4){0,0,0,0}; }

        #pragma unroll
        for (int st = 0; st < 8; st++) {
            bf16x8 af0 = cvt8(fv0[0][0], fv0[0][1]);
            bf16x8 af1 = cvt8(fv0[1][0], fv0[1][1]);
            bf16x8 b0 = cvt8(fw0[0], fw0[1]);
            bf16x8 b1 = cvt8(fw1[0], fw1[1]);
            if (st < 7) {
                int o = (st + 1) * 32;
                #pragma unroll
                for (int m = 0; m < 2; m++) {
                    fv0[m][0] = *(const float4*)(vb[m] + o);
                    fv0[m][1] = *(const float4*)(vb[m] + o + 4);
                }
                fw0[0] = *(const float4*)(wb0 + o);
                fw0[1] = *(const float4*)(wb0 + o + 4);
                if (wb1) { fw1[0] = *(const float4*)(wb1 + o); fw1[1] = *(const float4*)(wb1 + o + 4); }
            }
            a0[0] = __builtin_amdgcn_mfma_f32_16x16x32_bf16(af0, b0, a0[0], 0, 0, 0);
            a0[1] = __builtin_amdgcn_mfma_f32_16x16x32_bf16(af1, b0, a0[1], 0, 0, 0);
            if (wv == 3) {
                a1[0] = __builtin_amdgcn_mfma_f32_16x16x32_bf16(af0, b1, a1[0], 0, 0, 0);
                a1[1] = __builtin_amdgcn_mfma_f32_16x16x32_bf16(af1, b1, a1[1], 0, 0, 0);
            }
        }

        {
            int col = wv * 16 + l15;
            float bb = blin[c * Vdim + col];
            #pragma unroll
            for (int m = 0; m < 2; m++)
                #pragma unroll
                for (int reg = 0; reg < 4; reg++)
                    Lg[(m * 16 + quad * 4 + reg) * 84 + col] = a0[m][reg] + bb;
            if (wv == 3) {
                int col1 = 64 + l15;
                float bb1 = (l15 < 2) ? bec[l15] : ((l15 < 7) ? brel[l15 - 2] : 0.f);
                #pragma unroll
                for (int m = 0; m < 2; m++)
                    #pragma unroll
                    for (int reg = 0; reg < 4; reg++)
                        Lg[(m * 16 + quad * 4 + reg) * 84 + col1] = a1[m][reg] + bb1;
            }
        }
        __syncthreads();
        for (int rr = 0; rr < 8; rr++) {
            int r = wv * 8 + rr;
            if (r >= rcount) break;
            int orig = __shfl(reg_row, r);
            float lg = Lg[r * 84 + l];
            float mx = lg;
            for (int ss = 32; ss >= 1; ss >>= 1) mx = fmaxf(mx, __shfl_xor(mx, ss));
            float sm = expf(lg - mx);
            for (int ss = 32; ss >= 1; ss >>= 1) sm += __shfl_xor(sm, ss);
            float lt = __shfl(lg, true_idx[orig]);
            float loss = mx + logf(sm) - lt;
            if (l == 0) {
                float l0 = Lg[r * 84 + 64], l1 = Lg[r * 84 + 65];
                float me2 = fmaxf(l0, l1);
                loss += me2 + logf(expf(l0 - me2) + expf(l1 - me2)) - ((ec_idx[orig] == 0) ? l0 : l1);
                float rl[5] = { Lg[r * 84 + 66], Lg[r * 84 + 67], Lg[r * 84 + 68], Lg[r * 84 + 69], Lg[r * 84 + 70] };
                float mr = rl[0];
                #pragma unroll
                for (int i = 1; i < 5; i++) mr = fmaxf(mr, rl[i]);
                float sr = 0.f;
                #pragma unroll
                for (int i = 0; i < 5; i++) sr += expf(rl[i] - mr);
                loss += mr + logf(sr) - rl[rel_idx[orig]];
                out[(size_t)orig * OUTS] = loss;
            }
        }
    }
}

extern "C" void kernel_launch(void* const* d_in, const int* in_sizes, int n_in,
                              void* d_out, int out_size, void* d_ws, size_t ws_size,
                              hipStream_t stream) {
    const float* vec      = (const float*)d_in[0];
    const float* inp      = (const float*)d_in[1];
    const float* h_prev   = (const float*)d_in[2];
    const float* c_prev   = (const float*)d_in[3];
    const float* Wlin     = (const float*)d_in[4];
    const float* blin     = (const float*)d_in[5];
    const float* Wec      = (const float*)d_in[6];
    const float* bec      = (const float*)d_in[7];
    const float* Wrel     = (const float*)d_in[8];
    const float* brel     = (const float*)d_in[9];
    const float* W_ih     = (const float*)d_in[10];
    const float* b_ih     = (const float*)d_in[11];
    const float* W_hh     = (const float*)d_in[12];
    const float* b_hh     = (const float*)d_in[13];
    const int*   category = (const int*)d_in[14];
    const int*   cell_id  = (const int*)d_in[15];
    const int*   true_idx = (const int*)d_in[16];
    const int*   ec_idx   = (const int*)d_in[17];
    const int*   rel_idx  = (const int*)d_in[18];
    float* out = (float*)d_out;
    int* ws = (int*)d_ws;

    k_bucket<<<2, 1024, 0, stream>>>(cell_id, category, ws);
    k_main<<<MAIN_GRID, 256, 0, stream>>>(
        vec, inp, h_prev, c_prev, Wlin, blin, Wec, bec, Wrel, brel,
        W_ih, b_ih, W_hh, b_hh, true_idx, ec_idx, rel_idx, ws, out);
}

// Round 4
// 140.402 us; speedup vs baseline: 1.4003x; 1.4003x over previous
//
#include <hip/hip_runtime.h>
#include <hip/hip_bf16.h>
#include <math.h>

#define Nn 4096
#define Hdim 256
#define Edim 128
#define Cdim 32
#define Vdim 64
#define Kdim 20
#define G4H 1024
#define OUTS 513

// bucketing workspace (ints)
#define SK 512
#define SC 256
#define RK_OFF 64
#define RC_OFF (RK_OFF + Kdim * SK)      // 10304
#define NLI 18496                         // lstm item count
#define NSI 18497                         // loss item count
#define ITL 18498                         // lstm items (<= 592, cap 640)
#define ITS (ITL + 640)                   // loss items (<= 288, cap 320)

#define LSTM_REGION 592
#define LOSS_REGION 320
#define GRID (LSTM_REGION + LOSS_REGION)  // 912

typedef short bf16x8 __attribute__((ext_vector_type(8)));
typedef float f32x4 __attribute__((ext_vector_type(4)));

__device__ __forceinline__ float sigmoidf_(float x) { return 1.0f / (1.0f + expf(-x)); }

__device__ __forceinline__ bf16x8 cvt8(float4 f0, float4 f1) {
    bf16x8 r;
    __hip_bfloat16 h;
    h = __float2bfloat16(f0.x); r[0] = *(short*)&h;
    h = __float2bfloat16(f0.y); r[1] = *(short*)&h;
    h = __float2bfloat16(f0.z); r[2] = *(short*)&h;
    h = __float2bfloat16(f0.w); r[3] = *(short*)&h;
    h = __float2bfloat16(f1.x); r[4] = *(short*)&h;
    h = __float2bfloat16(f1.y); r[5] = *(short*)&h;
    h = __float2bfloat16(f1.z); r[6] = *(short*)&h;
    h = __float2bfloat16(f1.w); r[7] = *(short*)&h;
    return r;
}

__device__ __forceinline__ void gl_lds16(const float* g, void* l) {
    __builtin_amdgcn_global_load_lds((const __attribute__((address_space(1))) void*)g,
                                     (__attribute__((address_space(3))) void*)l, 16, 0, 0);
}

__device__ __forceinline__ int swz(int r) { return ((r & 3) << 1) | ((r >> 2) & 1); }

// ================= setup: bucket rows + build compact work lists =================
__global__ __launch_bounds__(1024) void k_bucket(const int* __restrict__ cell_id,
                                                 const int* __restrict__ category,
                                                 int* __restrict__ ws) {
    __shared__ int cnt[32];
    __shared__ int off[33];
    int t = threadIdx.x;
    if (t < 32) cnt[t] = 0;
    __syncthreads();
    int i0 = t * 4;
    if (blockIdx.x == 0) {
        int4 v = ((const int4*)cell_id)[t];
        int r;
        r = atomicAdd(&cnt[v.x], 1); if (r < SK) ws[RK_OFF + v.x * SK + r] = i0 + 0;
        r = atomicAdd(&cnt[v.y], 1); if (r < SK) ws[RK_OFF + v.y * SK + r] = i0 + 1;
        r = atomicAdd(&cnt[v.z], 1); if (r < SK) ws[RK_OFF + v.z * SK + r] = i0 + 2;
        r = atomicAdd(&cnt[v.w], 1); if (r < SK) ws[RK_OFF + v.w * SK + r] = i0 + 3;
        __syncthreads();
        if (t == 0) {
            int a = 0;
            for (int kk = 0; kk < Kdim; kk++) { off[kk] = a; a += (min(cnt[kk], SK) + 31) >> 5; }
            ws[NLI] = a * 4;
        }
        __syncthreads();
        if (t < Kdim) {
            int ns = (min(cnt[t], SK) + 31) >> 5;
            int base = off[t];
            for (int s = 0; s < ns; s++)
                for (int hq = 0; hq < 4; hq++)
                    ws[ITL + (base + s) * 4 + hq] = t | (s << 8) | (hq << 16);
        }
        if (t < 32) ws[t] = min(cnt[t], SK);
    } else {
        int4 v = ((const int4*)category)[t];
        int r;
        r = atomicAdd(&cnt[v.x], 1); if (r < SC) ws[RC_OFF + v.x * SC + r] = i0 + 0;
        r = atomicAdd(&cnt[v.y], 1); if (r < SC) ws[RC_OFF + v.y * SC + r] = i0 + 1;
        r = atomicAdd(&cnt[v.z], 1); if (r < SC) ws[RC_OFF + v.z * SC + r] = i0 + 2;
        r = atomicAdd(&cnt[v.w], 1); if (r < SC) ws[RC_OFF + v.w * SC + r] = i0 + 3;
        __syncthreads();
        if (t == 0) {
            int a = 0;
            for (int cc = 0; cc < Cdim; cc++) { off[cc] = a; a += (min(cnt[cc], SC) + 15) >> 4; }
            ws[NSI] = a;
        }
        __syncthreads();
        if (t < Cdim) {
            int ns = (min(cnt[t], SC) + 15) >> 4;
            int base = off[t];
            for (int s = 0; s < ns; s++)
                ws[ITS + base + s] = t | (s << 8);
        }
        if (t < 32) ws[32 + t] = min(cnt[t], SC);
    }
}

// ================= main: LDS-DMA staged MFMA, fine-grained tiles =================
// Fragment convention: lane l = 16*q + r holds M[row r][k = 8q .. 8q+7].
// LDS buffers row-major [rows][32 floats]; slot j of row r holds global
// k-chunk (j ^ swz(r)) so reads at p0 = (quad*2)^swz(l15) are conflict-free.
__global__ __launch_bounds__(256, 4) void k_main(
    const float* __restrict__ vec, const float* __restrict__ inp,
    const float* __restrict__ h_prev, const float* __restrict__ c_prev,
    const float* __restrict__ Wlin, const float* __restrict__ blin,
    const float* __restrict__ Wec, const float* __restrict__ bec,
    const float* __restrict__ Wrel, const float* __restrict__ brel,
    const float* __restrict__ W_ih, const float* __restrict__ b_ih,
    const float* __restrict__ W_hh, const float* __restrict__ b_hh,
    const int* __restrict__ true_idx, const int* __restrict__ ec_idx, const int* __restrict__ rel_idx,
    const int* __restrict__ ws,
    float* __restrict__ out)
{
    __shared__ __align__(16) char smem[36864];

    int b = blockIdx.x, t = threadIdx.x;
    int w = t >> 6, l = t & 63;
    int l15 = l & 15, quad = l >> 4;
    int lrow8 = l >> 3, lslot = l & 7;
    int p0 = (quad * 2) ^ swz(l15);

    if (b < LSTM_REGION) {
        // ---- LSTM: 32 rows x 64 hcols (hq quarter) x 4 gates; K = 384, BK = 32 ----
        if (b >= ws[NLI]) return;
        int item = ws[ITL + b];
        int k = item & 255, s = (item >> 8) & 255, hq = item >> 16;
        int cntk = ws[k];
        int rcount = min(32, cntk - s * 32);
        int reg_row = ws[RK_OFF + k * SK + s * 32 + min(l & 31, rcount - 1)];

        float* Wb = (float*)smem;             // 256 rows x 32 f32 (32 KB)
        float* Xb = (float*)(smem + 32768);   // 32 rows x 32 f32 (4 KB)
        const float* Wih_k = W_ih + (size_t)k * G4H * Edim;
        const float* Whh_k = W_hh + (size_t)k * G4H * Hdim;

        int xr = w * 8 + lrow8;               // X row staged by this lane
        int xrow = __shfl(reg_row, xr);
        int xg = lslot ^ swz(xr);

        // hoisted epilogue operands
        int h = hq * 64 + w * 16 + l15;
        float bs[4];
        #pragma unroll
        for (int g = 0; g < 4; g++)
            bs[g] = b_ih[(size_t)k * G4H + g * Hdim + h] + b_hh[(size_t)k * G4H + g * Hdim + h];
        float cp[2][4];
        #pragma unroll
        for (int m = 0; m < 2; m++)
            #pragma unroll
            for (int reg = 0; reg < 4; reg++) {
                int r = m * 16 + quad * 4 + reg;
                int row = __shfl(reg_row, r);
                cp[m][reg] = c_prev[(size_t)row * Hdim + h];
            }

        f32x4 acc[2][4];
        #pragma unroll
        for (int m = 0; m < 2; m++)
            #pragma unroll
            for (int g = 0; g < 4; g++)
                acc[m][g] = (f32x4){0.f, 0.f, 0.f, 0.f};

        for (int st = 0; st < 12; st++) {
            int k0 = st * 32;
            const float* Wsrc; int stride, ko;
            if (k0 < Edim) { Wsrc = Wih_k; stride = Edim; ko = k0; }
            else           { Wsrc = Whh_k; stride = Hdim; ko = k0 - Edim; }
            __syncthreads();
            #pragma unroll
            for (int j = 0; j < 8; j++) {
                int r = w * 64 + j * 8 + lrow8;
                int g = lslot ^ swz(r);
                int gate = r >> 6, hl = r & 63;
                gl_lds16(Wsrc + (size_t)(gate * Hdim + hq * 64 + hl) * stride + ko + g * 4,
                         Wb + (w * 64 + j * 8) * 32);
            }
            {
                const float* Xs = (k0 < Edim) ? inp + (size_t)xrow * Edim + ko
                                              : h_prev + (size_t)xrow * Hdim + ko;
                gl_lds16(Xs + xg * 4, Xb + (w * 8) * 32);
            }
            __syncthreads();

            bf16x8 af[2], bfr[4];
            #pragma unroll
            for (int m = 0; m < 2; m++) {
                int row = m * 16 + l15;
                float4 lo = *(float4*)(Xb + row * 32 + p0 * 4);
                float4 hi = *(float4*)(Xb + row * 32 + (p0 ^ 1) * 4);
                af[m] = cvt8(lo, hi);
            }
            #pragma unroll
            for (int g = 0; g < 4; g++) {
                int row = g * 64 + w * 16 + l15;
                float4 lo = *(float4*)(Wb + row * 32 + p0 * 4);
                float4 hi = *(float4*)(Wb + row * 32 + (p0 ^ 1) * 4);
                bfr[g] = cvt8(lo, hi);
            }
            #pragma unroll
            for (int m = 0; m < 2; m++)
                #pragma unroll
                for (int g = 0; g < 4; g++)
                    acc[m][g] = __builtin_amdgcn_mfma_f32_16x16x32_bf16(af[m], bfr[g], acc[m][g], 0, 0, 0);
        }

        #pragma unroll
        for (int m = 0; m < 2; m++) {
            #pragma unroll
            for (int reg = 0; reg < 4; reg++) {
                int r = m * 16 + quad * 4 + reg;
                int row = __shfl(reg_row, r);
                if (r < rcount) {
                    float iv = acc[m][0][reg] + bs[0];
                    float fv = acc[m][1][reg] + bs[1];
                    float gv = acc[m][2][reg] + bs[2];
                    float ov = acc[m][3][reg] + bs[3];
                    float cn = sigmoidf_(fv) * cp[m][reg] + sigmoidf_(iv) * tanhf(gv);
                    float hn = sigmoidf_(ov) * tanhf(cn);
                    out[(size_t)row * OUTS + 1 + h] = hn;
                    out[(size_t)row * OUTS + 1 + Hdim + h] = cn;
                }
            }
        }
    } else {
        // ---- loss: 16 rows x 80 logits; K = 256, BK = 32 ----
        int b2 = b - LSTM_REGION;
        if (b2 >= ws[NSI]) return;
        int item = ws[ITS + b2];
        int c = item & 255, s = item >> 8;
        int cntc = ws[32 + c];
        int rcount = min(16, cntc - s * 16);
        int reg_row = ws[RC_OFF + c * SC + s * 16 + min(l & 15, rcount - 1)];

        float* Wb = (float*)smem;             // 80 rows x 32 f32 (10240 B)
        float* Vb = (float*)(smem + 10240);   // 16 rows x 32 f32 (2048 B)
        float* Lg = (float*)(smem + 12288);   // 16 x 84 f32 (5376 B)

        int xr = (w >= 2) ? ((w - 2) * 8 + lrow8) : 0;
        int xrow = __shfl(reg_row, xr);
        int xg = lslot ^ swz(xr);

        f32x4 a0 = (f32x4){0.f, 0.f, 0.f, 0.f};
        f32x4 a1 = (f32x4){0.f, 0.f, 0.f, 0.f};

        for (int st = 0; st < 8; st++) {
            int ko = st * 32;
            __syncthreads();
            for (int n = w; n < 10; n += 4) {
                int r = n * 8 + lrow8;
                int g = lslot ^ swz(r);
                const float* srcW;
                if (r < 64)      srcW = Wlin + ((size_t)c * Vdim + r) * Hdim;
                else if (r < 66) srcW = Wec + (size_t)(r - 64) * Hdim;
                else if (r < 71) srcW = Wrel + (size_t)(r - 66) * Hdim;
                else             srcW = Wlin + (size_t)c * Vdim * Hdim;
                gl_lds16(srcW + ko + g * 4, Wb + n * 8 * 32);
            }
            if (w >= 2)
                gl_lds16(vec + (size_t)xrow * Hdim + ko + xg * 4, Vb + ((w - 2) * 8) * 32);
            __syncthreads();

            bf16x8 af;
            {
                float4 lo = *(float4*)(Vb + l15 * 32 + p0 * 4);
                float4 hi = *(float4*)(Vb + l15 * 32 + (p0 ^ 1) * 4);
                af = cvt8(lo, hi);
            }
            {
                int row = w * 16 + l15;
                float4 lo = *(float4*)(Wb + row * 32 + p0 * 4);
                float4 hi = *(float4*)(Wb + row * 32 + (p0 ^ 1) * 4);
                bf16x8 b0 = cvt8(lo, hi);
                a0 = __builtin_amdgcn_mfma_f32_16x16x32_bf16(af, b0, a0, 0, 0, 0);
            }
            if (w == 3) {
                int row = 64 + l15;
                float4 lo = *(float4*)(Wb + row * 32 + p0 * 4);
                float4 hi = *(float4*)(Wb + row * 32 + (p0 ^ 1) * 4);
                bf16x8 b1 = cvt8(lo, hi);
                a1 = __builtin_amdgcn_mfma_f32_16x16x32_bf16(af, b1, a1, 0, 0, 0);
            }
        }
        __syncthreads();
        {
            int col = w * 16 + l15;
            float bb = blin[c * Vdim + col];
            #pragma unroll
            for (int reg = 0; reg < 4; reg++)
                Lg[(quad * 4 + reg) * 84 + col] = a0[reg] + bb;
            if (w == 3) {
                int col1 = 64 + l15;
                float bb1 = (l15 < 2) ? bec[l15] : ((l15 < 7) ? brel[l15 - 2] : 0.f);
                #pragma unroll
                for (int reg = 0; reg < 4; reg++)
                    Lg[(quad * 4 + reg) * 84 + col1] = a1[reg] + bb1;
            }
        }
        __syncthreads();
        for (int rr = 0; rr < 4; rr++) {
            int r = w * 4 + rr;
            if (r >= rcount) break;
            int orig = __shfl(reg_row, r);
            float lg = Lg[r * 84 + l];
            float mx = lg;
            for (int ss = 32; ss >= 1; ss >>= 1) mx = fmaxf(mx, __shfl_xor(mx, ss));
            float sm = expf(lg - mx);
            for (int ss = 32; ss >= 1; ss >>= 1) sm += __shfl_xor(sm, ss);
            float lt = __shfl(lg, true_idx[orig]);
            float loss = mx + logf(sm) - lt;
            if (l == 0) {
                float l0 = Lg[r * 84 + 64], l1 = Lg[r * 84 + 65];
                float me2 = fmaxf(l0, l1);
                loss += me2 + logf(expf(l0 - me2) + expf(l1 - me2)) - ((ec_idx[orig] == 0) ? l0 : l1);
                float rl[5] = { Lg[r * 84 + 66], Lg[r * 84 + 67], Lg[r * 84 + 68], Lg[r * 84 + 69], Lg[r * 84 + 70] };
                float mr = rl[0];
                #pragma unroll
                for (int i = 1; i < 5; i++) mr = fmaxf(mr, rl[i]);
                float sr = 0.f;
                #pragma unroll
                for (int i = 0; i < 5; i++) sr += expf(rl[i] - mr);
                loss += mr + logf(sr) - rl[rel_idx[orig]];
                out[(size_t)orig * OUTS] = loss;
            }
        }
    }
}

extern "C" void kernel_launch(void* const* d_in, const int* in_sizes, int n_in,
                              void* d_out, int out_size, void* d_ws, size_t ws_size,
                              hipStream_t stream) {
    const float* vec      = (const float*)d_in[0];
    const float* inp      = (const float*)d_in[1];
    const float* h_prev   = (const float*)d_in[2];
    const float* c_prev   = (const float*)d_in[3];
    const float* Wlin     = (const float*)d_in[4];
    const float* blin     = (const float*)d_in[5];
    const float* Wec      = (const float*)d_in[6];
    const float* bec      = (const float*)d_in[7];
    const float* Wrel     = (const float*)d_in[8];
    const float* brel     = (const float*)d_in[9];
    const float* W_ih     = (const float*)d_in[10];
    const float* b_ih     = (const float*)d_in[11];
    const float* W_hh     = (const float*)d_in[12];
    const float* b_hh     = (const float*)d_in[13];
    const int*   category = (const int*)d_in[14];
    const int*   cell_id  = (const int*)d_in[15];
    const int*   true_idx = (const int*)d_in[16];
    const int*   ec_idx   = (const int*)d_in[17];
    const int*   rel_idx  = (const int*)d_in[18];
    float* out = (float*)d_out;
    int* ws = (int*)d_ws;

    k_bucket<<<2, 1024, 0, stream>>>(cell_id, category, ws);
    k_main<<<GRID, 256, 0, stream>>>(
        vec, inp, h_prev, c_prev, Wlin, blin, Wec, bec, Wrel, brel,
        W_ih, b_ih, W_hh, b_hh, true_idx, ec_idx, rel_idx, ws, out);
}